// Round 14
// baseline (233.760 us; speedup 1.0000x reference)
//
#include <hip/hip_runtime.h>
#include <stdint.h>

#define BATCH 16384
#define SDIM 512
#define ADIM 64
#define XDIM 576      // SDIM + ADIM
#define HDIM 1024
#define NQD 64
#define QED 64

typedef __attribute__((ext_vector_type(8))) short short8;
typedef __attribute__((ext_vector_type(4))) float f32x4;

static __device__ inline unsigned short f2bf(float f) {
  unsigned int u = __float_as_uint(f);
  unsigned int r = (u + 0x7fffu + ((u >> 16) & 1u)) >> 16;
  return (unsigned short)r;
}
static __device__ inline float bf2f(unsigned short u) {
  return __uint_as_float(((unsigned int)u) << 16);
}

static __device__ inline void gload_lds16(const void* g, void* l) {
  __builtin_amdgcn_global_load_lds(
      (const __attribute__((address_space(1))) uint32_t*)g,
      (__attribute__((address_space(3))) uint32_t*)l, 16, 0, 0);
}

// ---------------- merged conversion kernel ----------------

__global__ __launch_bounds__(256) void prep(const float* __restrict__ st,
                                            const float* __restrict__ ac,
                                            unsigned short* __restrict__ xb,
                                            const float* __restrict__ w1s,
                                            unsigned short* __restrict__ w1d,
                                            const float* __restrict__ w2s,
                                            unsigned short* __restrict__ w2d) {
  const int nx = BATCH * XDIM / 4;
  const int n1 = 2 * HDIM * XDIM / 4;
  const int n2 = 2 * HDIM * HDIM / 4;
  for (int i = blockIdx.x * blockDim.x + threadIdx.x; i < nx + n1 + n2;
       i += gridDim.x * blockDim.x) {
    float4 v;
    unsigned short* dst;
    int di;
    if (i < nx) {
      const int e = i * 4;
      const int b = e / XDIM;
      const int j = e - b * XDIM;
      if (j < SDIM) v = *(const float4*)(st + (size_t)b * SDIM + j);
      else          v = *(const float4*)(ac + (size_t)b * ADIM + (j - SDIM));
      dst = xb; di = i;
    } else if (i < nx + n1) {
      di = i - nx; v = ((const float4*)w1s)[di]; dst = w1d;
    } else {
      di = i - nx - n1; v = ((const float4*)w2s)[di]; dst = w2d;
    }
    ushort4 o;
    o.x = f2bf(v.x); o.y = f2bf(v.y); o.z = f2bf(v.z); o.w = f2bf(v.w);
    ((ushort4*)dst)[di] = o;
  }
}

// ---------------- tau embedding head contribution (exact fp32) ----------------

__global__ void qtau_kernel(const float* __restrict__ We1, const float* __restrict__ be1,
                            const float* __restrict__ We2, const float* __restrict__ be2,
                            const float* __restrict__ Wh,  const float* __restrict__ bh,
                            float* __restrict__ qtau) {
  const int c = blockIdx.x >> 6;
  const int nq = blockIdx.x & 63;
  const int q = threadIdx.x;  // 64 threads = 1 wave
  const float tau = (float)nq / 64.0f + 0.0078125f;
  float acc = be2[c * 64 + q];
  for (int e = 0; e < 64; ++e) {
    const float t1 = fmaxf(tau * We1[c * 64 + e] + be1[c * 64 + e], 0.0f);
    acc += t1 * We2[(c * 64 + q) * 64 + e];
  }
  float v = acc * Wh[c * (HDIM + QED) + HDIM + q];
  #pragma unroll
  for (int off = 32; off; off >>= 1) v += __shfl_xor(v, off);
  if (q == 0) qtau[c * 64 + nq] = v + bh[c];
}

// ---------------- per-row stats reduce: 16 slots -> (mu, rsig) -------------

__global__ __launch_bounds__(256) void stats_reduce(const float2* __restrict__ pstat,
                                                    float2* __restrict__ musig) {
  const int i = blockIdx.x * 256 + threadIdx.x;  // 0 .. 2*BATCH-1
  float s = 0.f, q = 0.f;
  #pragma unroll
  for (int k = 0; k < 16; ++k) {
    const float2 v = pstat[(size_t)i * 16 + k];
    s += v.x; q += v.y;
  }
  const float mu = s * (1.0f / 1024.0f);
  const float var = q * (1.0f / 1024.0f) - mu * mu;
  float2 o; o.x = mu; o.y = rsqrtf(var + 1e-5f);
  musig[i] = o;
}

// ---------------- critic-batched 256x128 bf16 GEMM -------------------------
// R12 skeleton (16x16x32, proven best): 8 waves (4M x 2N), BK=32, 48 KiB LDS
// dbuf, both-sides slot swizzle, packed LDS-transpose epilogue.
// STATS: epilogue also emits per-row partial (sum,sumsq) of this block's
//        128-col slice (on bf16-ROUNDED values = exact old-ln numerics),
//        butterfly over 16 lanes, slot (n*2+wn) -> pstat. Deterministic.
// XFORM: A-fragments get LN+ReLU applied at frag-read:
//        y = relu(fma(fma(x, rs, -mu*rs), g[k], beta[k])), packed back to
//        bf16 via v_cvt_pk_bf16_f32 (RNE == f2bf). Replaces the ln pass.

template <int K, bool STATS, bool XFORM>
__global__ __launch_bounds__(512, 4) void gemm_bc(const unsigned short* __restrict__ Abase,
                                                  size_t aCritStride,
                                                  const unsigned short* __restrict__ Wbase,
                                                  const float* __restrict__ biasBase,
                                                  unsigned short* __restrict__ Cbase,
                                                  const float2* __restrict__ musigB,
                                                  const float* __restrict__ gB,
                                                  const float* __restrict__ bB,
                                                  float2* __restrict__ pstat) {
  constexpr int NT = K / 32;
  __shared__ unsigned short As[2][256][32];  // 32 KiB
  __shared__ unsigned short Bs[2][128][32];  // 16 KiB (pool reused by epilogue)

  const int tid  = threadIdx.x;
  const int lane = tid & 63;
  const int wave = tid >> 6;
  const int wm = wave >> 1;   // 0..3 -> rows [wm*64, wm*64+64)
  const int wn = wave & 1;    // 0..1 -> cols [wn*64, wn*64+64)

  const int bid = (int)blockIdx.x;
  const int L = (bid & 7) * 128 + (bid >> 3);
  const int n = L & 7;
  const int cidx = (L >> 3) & 1;
  const int m = L >> 4;
  const int mBase = m * 256;
  const int nBase = n * 128;

  const unsigned short* A = Abase + aCritStride * (size_t)cidx;
  const unsigned short* W = Wbase + (size_t)cidx * HDIM * K;
  const float* bias = biasBase + cidx * HDIM;
  unsigned short* C = Cbase + (size_t)cidx * BATCH * HDIM;
  const float2* musig = XFORM ? (musigB + (size_t)cidx * BATCH) : nullptr;
  const float* gv = XFORM ? (gB + cidx * HDIM) : nullptr;
  const float* bv = XFORM ? (bB + cidx * HDIM) : nullptr;

  auto stage = [&](int buf, int kt) {
    #pragma unroll
    for (int i = 0; i < 2; ++i) {
      const int flat = i * 512 + tid;
      const int row  = flat >> 2;
      const int ls   = (flat & 3) ^ ((row >> 1) & 3);
      gload_lds16(A + (size_t)(mBase + row) * K + kt * 32 + ls * 8,
                  &As[buf][0][0] + (size_t)flat * 8);
    }
    {
      const int row = tid >> 2;
      const int ls  = (tid & 3) ^ ((row >> 1) & 3);
      gload_lds16(W + (size_t)(nBase + row) * K + kt * 32 + ls * 8,
                  &Bs[buf][0][0] + (size_t)tid * 8);
    }
  };

  f32x4 acc[4][4];
  #pragma unroll
  for (int fm = 0; fm < 4; ++fm)
    #pragma unroll
    for (int fn = 0; fn < 4; ++fn) {
      f32x4 z = {0.f, 0.f, 0.f, 0.f};
      acc[fm][fn] = z;
    }

  stage(0, 0);
  __syncthreads();

  for (int t = 0; t < NT; ++t) {
    const int buf = t & 1;
    if (t + 1 < NT) stage(buf ^ 1, t + 1);

    short8 af[4], bf[4];
    if constexpr (XFORM) {
      const int k0 = t * 32 + (lane >> 4) * 8;
      const float4 g0 = *(const float4*)(gv + k0);
      const float4 g1 = *(const float4*)(gv + k0 + 4);
      const float4 b0 = *(const float4*)(bv + k0);
      const float4 b1 = *(const float4*)(bv + k0 + 4);
      const float gk[8] = {g0.x, g0.y, g0.z, g0.w, g1.x, g1.y, g1.z, g1.w};
      const float bk[8] = {b0.x, b0.y, b0.z, b0.w, b1.x, b1.y, b1.z, b1.w};
      #pragma unroll
      for (int fm = 0; fm < 4; ++fm) {
        const int r  = wm * 64 + fm * 16 + (lane & 15);
        const int ps = (lane >> 4) ^ ((r >> 1) & 3);
        union { short8 s; unsigned int u[4]; } rd, cv;
        rd.s = *(const short8*)&As[buf][r][ps * 8];
        const float2 ms = musig[mBase + r];
        const float rsf = ms.y;
        const float nmu = -ms.x * rsf;
        #pragma unroll
        for (int d = 0; d < 4; ++d) {
          const unsigned int w = rd.u[d];
          const float xlo = __uint_as_float(w << 16);
          const float xhi = __uint_as_float(w & 0xffff0000u);
          const float ylo = fmaxf(fmaf(fmaf(xlo, rsf, nmu), gk[2 * d],     bk[2 * d]),     0.f);
          const float yhi = fmaxf(fmaf(fmaf(xhi, rsf, nmu), gk[2 * d + 1], bk[2 * d + 1]), 0.f);
          asm("v_cvt_pk_bf16_f32 %0, %1, %2" : "=v"(cv.u[d]) : "v"(ylo), "v"(yhi));
        }
        af[fm] = cv.s;
      }
    } else {
      #pragma unroll
      for (int fm = 0; fm < 4; ++fm) {
        const int r  = wm * 64 + fm * 16 + (lane & 15);
        const int ps = (lane >> 4) ^ ((r >> 1) & 3);
        af[fm] = *(const short8*)&As[buf][r][ps * 8];
      }
    }
    #pragma unroll
    for (int fn = 0; fn < 4; ++fn) {
      const int r  = wn * 64 + fn * 16 + (lane & 15);
      const int ps = (lane >> 4) ^ ((r >> 1) & 3);
      bf[fn] = *(const short8*)&Bs[buf][r][ps * 8];
    }

    __builtin_amdgcn_s_setprio(1);
    #pragma unroll
    for (int fm = 0; fm < 4; ++fm)
      #pragma unroll
      for (int fn = 0; fn < 4; ++fn)
        acc[fm][fn] = __builtin_amdgcn_mfma_f32_16x16x32_bf16(af[fm], bf[fn],
                                                              acc[fm][fn], 0, 0, 0);
    __builtin_amdgcn_s_setprio(0);
    __syncthreads();
  }

  // ---- packed epilogue: LDS transpose -> full-128B-line stores (+ stats) ----
  __syncthreads();  // all waves done reading As/Bs before patch overwrite
  unsigned short* patch = ((unsigned short*)&As[0][0][0]) + wave * 2304;  // 32x72 shorts

  float bcol[4];
  #pragma unroll
  for (int fn = 0; fn < 4; ++fn)
    bcol[fn] = bias[nBase + wn * 64 + fn * 16 + (lane & 15)];

  const int cBase = nBase + wn * 64;

  float sA[16], qA[16];
  if constexpr (STATS) {
    #pragma unroll
    for (int i = 0; i < 16; ++i) { sA[i] = 0.f; qA[i] = 0.f; }
  }

  #pragma unroll
  for (int p = 0; p < 2; ++p) {
    #pragma unroll
    for (int f2 = 0; f2 < 2; ++f2) {
      const int fm = p * 2 + f2;
      #pragma unroll
      for (int fn = 0; fn < 4; ++fn) {
        const int rl = f2 * 16 + (lane >> 4) * 4;
        const int cl = fn * 16 + (lane & 15);
        #pragma unroll
        for (int j = 0; j < 4; ++j) {
          const unsigned short o = f2bf(acc[fm][fn][j] + bcol[fn]);
          patch[(rl + j) * 72 + cl] = o;
          if constexpr (STATS) {
            const float vb = bf2f(o);
            sA[fm * 4 + j] += vb;
            qA[fm * 4 + j] += vb * vb;
          }
        }
      }
    }
    #pragma unroll
    for (int k = 0; k < 4; ++k) {
      const int rl = k * 8 + (lane >> 3);
      const short8 v = *(const short8*)&patch[rl * 72 + (lane & 7) * 8];
      const int rowg = mBase + wm * 64 + p * 32 + rl;
      *(short8*)(C + (size_t)rowg * HDIM + cBase + (lane & 7) * 8) = v;
    }
  }

  if constexpr (STATS) {
    #pragma unroll
    for (int off = 1; off < 16; off <<= 1)
      #pragma unroll
      for (int i = 0; i < 16; ++i) {
        sA[i] += __shfl_xor(sA[i], off);
        qA[i] += __shfl_xor(qA[i], off);
      }
    if ((lane & 15) == 0) {
      const int slot = n * 2 + wn;
      #pragma unroll
      for (int i = 0; i < 16; ++i) {
        const int p = i >> 3, f2 = (i >> 2) & 1, j = i & 3;
        const int row = mBase + wm * 64 + p * 32 + f2 * 16 + (lane >> 4) * 4 + j;
        float2 o; o.x = sA[i]; o.y = qA[i];
        pstat[((size_t)cidx * BATCH + row) * 16 + slot] = o;
      }
    }
  }
}

// ---------------- critic-batched LayerNorm + ReLU + head -------------------

__global__ __launch_bounds__(256) void ln_head_bc(const unsigned short* __restrict__ Xb,
                                                  const float* __restrict__ gB,
                                                  const float* __restrict__ btB,
                                                  const float* __restrict__ WhB,
                                                  const float* __restrict__ qtB,
                                                  float* __restrict__ outB) {
  const int gb = blockIdx.x;
  const int c = gb >> 14;                 // BATCH = 2^14
  const int row = gb & (BATCH - 1);
  const unsigned short* X = Xb + ((size_t)c * BATCH + row) * HDIM;
  const float* g   = gB + c * HDIM;
  const float* bta = btB + c * HDIM;

  const int tid = threadIdx.x;
  const int lane = tid & 63;
  const int wave = tid >> 6;
  __shared__ float rs_[4], rq_[4], rp_[4];

  const ushort4 xv = ((const ushort4*)X)[tid];
  const float x0 = bf2f(xv.x), x1 = bf2f(xv.y), x2 = bf2f(xv.z), x3 = bf2f(xv.w);
  float s = x0 + x1 + x2 + x3;
  float q = x0 * x0 + x1 * x1 + x2 * x2 + x3 * x3;
  #pragma unroll
  for (int off = 32; off; off >>= 1) {
    s += __shfl_xor(s, off);
    q += __shfl_xor(q, off);
  }
  if (lane == 0) { rs_[wave] = s; rq_[wave] = q; }
  __syncthreads();
  s = rs_[0] + rs_[1] + rs_[2] + rs_[3];
  q = rq_[0] + rq_[1] + rq_[2] + rq_[3];
  const float mu = s * (1.0f / 1024.0f);
  const float var = q * (1.0f / 1024.0f) - mu * mu;
  const float rsig = rsqrtf(var + 1e-5f);

  const float4 gv = ((const float4*)g)[tid];
  const float4 bv = ((const float4*)bta)[tid];
  const float y0 = fmaxf((x0 - mu) * rsig * gv.x + bv.x, 0.0f);
  const float y1 = fmaxf((x1 - mu) * rsig * gv.y + bv.y, 0.0f);
  const float y2 = fmaxf((x2 - mu) * rsig * gv.z + bv.z, 0.0f);
  const float y3 = fmaxf((x3 - mu) * rsig * gv.w + bv.w, 0.0f);

  const float* Wh = WhB + c * (HDIM + QED);
  const float4 wv = ((const float4*)Wh)[tid];
  float p = y0 * wv.x + y1 * wv.y + y2 * wv.z + y3 * wv.w;
  #pragma unroll
  for (int off = 32; off; off >>= 1) p += __shfl_xor(p, off);
  if (lane == 0) rp_[wave] = p;
  __syncthreads();
  if (tid < 64) {
    const float qf = rp_[0] + rp_[1] + rp_[2] + rp_[3];
    outB[((size_t)c * BATCH + row) * NQD + tid] = qf + qtB[c * 64 + tid];
  }
}

// ---------------- launch ----------------

extern "C" void kernel_launch(void* const* d_in, const int* in_sizes, int n_in,
                              void* d_out, int out_size, void* d_ws, size_t ws_size,
                              hipStream_t stream) {
  (void)in_sizes; (void)n_in; (void)out_size; (void)ws_size;
  const float* state  = (const float*)d_in[0];
  const float* action = (const float*)d_in[1];
  const float* We1 = (const float*)d_in[2];
  const float* be1 = (const float*)d_in[3];
  const float* We2 = (const float*)d_in[4];
  const float* be2 = (const float*)d_in[5];
  const float* Wf1 = (const float*)d_in[6];
  const float* bW1 = (const float*)d_in[7];
  const float* g1  = (const float*)d_in[8];
  const float* bt1 = (const float*)d_in[9];
  const float* Wf2 = (const float*)d_in[10];
  const float* bW2 = (const float*)d_in[11];
  const float* g2  = (const float*)d_in[12];
  const float* bt2 = (const float*)d_in[13];
  const float* Wh  = (const float*)d_in[14];
  const float* bh  = (const float*)d_in[15];
  float* out = (float*)d_out;

  char* ws = (char*)d_ws;
  unsigned short* xb   = (unsigned short*)(ws);               // BATCH*576 bf16
  unsigned short* w1b  = (unsigned short*)(ws + 18874368);    // 2*1024*576 bf16
  unsigned short* w2b  = (unsigned short*)(ws + 21233664);    // 2*1024*1024 bf16
  float*          qtw  = (float*)(ws + 25427968);             // 2*64 f32
  unsigned short* ha   = (unsigned short*)(ws + 25428480);    // 2*BATCH*1024 bf16 -> ends 92,537,344
  unsigned short* hb   = (unsigned short*)(ws + 92537344);    // 2*BATCH*1024 bf16 -> ends 159,646,208

  // scratch carved from d_out (fully overwritten by ln_head_bc at call end):
  // pstat: 2*BATCH*16 float2 = 4 MB; musig: 2*BATCH float2 = 256 KB
  float2* pstat = (float2*)out;
  float2* musig = (float2*)(out + 2 * BATCH * 16 * 2);

  prep<<<2048, 256, 0, stream>>>(state, action, xb, Wf1, w1b, Wf2, w2b);
  qtau_kernel<<<128, 64, 0, stream>>>(We1, be1, We2, be2, Wh, bh, qtw);

  // layer 1 (+ per-row partial LN stats from registers)
  gemm_bc<XDIM, true, false><<<1024, 512, 0, stream>>>(
      xb, 0, w1b, bW1, ha, nullptr, nullptr, nullptr, pstat);
  stats_reduce<<<128, 256, 0, stream>>>(pstat, musig);
  // layer 2 with LN+ReLU applied to A at frag-read (ln pass deleted)
  gemm_bc<HDIM, false, true><<<1024, 512, 0, stream>>>(
      ha, (size_t)BATCH * HDIM, w2b, bW2, hb, musig, g1, bt1, nullptr);
  ln_head_bc<<<2 * BATCH, 256, 0, stream>>>(hb, g2, bt2, Wh, qtw, out);
}

// Round 15
// 196.410 us; speedup vs baseline: 1.1902x; 1.1902x over previous
//
#include <hip/hip_runtime.h>
#include <stdint.h>

#define BATCH 16384
#define SDIM 512
#define ADIM 64
#define XDIM 576      // SDIM + ADIM
#define HDIM 1024
#define NQD 64
#define QED 64

typedef __attribute__((ext_vector_type(8))) short short8;
typedef __attribute__((ext_vector_type(4))) float f32x4;

static __device__ inline unsigned short f2bf(float f) {
  unsigned int u = __float_as_uint(f);
  unsigned int r = (u + 0x7fffu + ((u >> 16) & 1u)) >> 16;
  return (unsigned short)r;
}
static __device__ inline float bf2f(unsigned short u) {
  return __uint_as_float(((unsigned int)u) << 16);
}

static __device__ inline void gload_lds16(const void* g, void* l) {
  __builtin_amdgcn_global_load_lds(
      (const __attribute__((address_space(1))) uint32_t*)g,
      (__attribute__((address_space(3))) uint32_t*)l, 16, 0, 0);
}

// ---------------- merged conversion + tau kernel ----------------
// blocks 0..2047: x concat + W_f1/W_f2 bf16 conversion (grid-stride)
// blocks 2048..2079: tau-embedding head contribution (4 units/block)

__global__ __launch_bounds__(256) void prep_all(const float* __restrict__ st,
                                                const float* __restrict__ ac,
                                                unsigned short* __restrict__ xb,
                                                const float* __restrict__ w1s,
                                                unsigned short* __restrict__ w1d,
                                                const float* __restrict__ w2s,
                                                unsigned short* __restrict__ w2d,
                                                const float* __restrict__ We1,
                                                const float* __restrict__ be1,
                                                const float* __restrict__ We2,
                                                const float* __restrict__ be2,
                                                const float* __restrict__ Wh,
                                                const float* __restrict__ bh,
                                                float* __restrict__ qtau) {
  const int bid = (int)blockIdx.x;
  if (bid >= 2048) {
    // ---- qtau part: exact fp32, one wave per (c, nq) unit ----
    const int u = (bid - 2048) * 4 + ((int)threadIdx.x >> 6);  // 0..127
    const int c = u >> 6;
    const int nq = u & 63;
    const int q = (int)threadIdx.x & 63;
    const float tau = (float)nq / 64.0f + 0.0078125f;
    float acc = be2[c * 64 + q];
    for (int e = 0; e < 64; ++e) {
      const float t1 = fmaxf(tau * We1[c * 64 + e] + be1[c * 64 + e], 0.0f);
      acc += t1 * We2[(c * 64 + q) * 64 + e];
    }
    float v = acc * Wh[c * (HDIM + QED) + HDIM + q];
    #pragma unroll
    for (int off = 32; off; off >>= 1) v += __shfl_xor(v, off);
    if (q == 0) qtau[c * 64 + nq] = v + bh[c];
    return;
  }
  const int nx = BATCH * XDIM / 4;
  const int n1 = 2 * HDIM * XDIM / 4;
  const int n2 = 2 * HDIM * HDIM / 4;
  for (int i = bid * 256 + (int)threadIdx.x; i < nx + n1 + n2; i += 2048 * 256) {
    float4 v;
    unsigned short* dst;
    int di;
    if (i < nx) {
      const int e = i * 4;
      const int b = e / XDIM;
      const int j = e - b * XDIM;
      if (j < SDIM) v = *(const float4*)(st + (size_t)b * SDIM + j);
      else          v = *(const float4*)(ac + (size_t)b * ADIM + (j - SDIM));
      dst = xb; di = i;
    } else if (i < nx + n1) {
      di = i - nx; v = ((const float4*)w1s)[di]; dst = w1d;
    } else {
      di = i - nx - n1; v = ((const float4*)w2s)[di]; dst = w2d;
    }
    ushort4 o;
    o.x = f2bf(v.x); o.y = f2bf(v.y); o.z = f2bf(v.z); o.w = f2bf(v.w);
    ((ushort4*)dst)[di] = o;
  }
}

// ---------------- critic-batched 256x128 bf16 GEMM (R12, proven best) ------
// Both critics in ONE dispatch (grid 1024). C[c][M,1024] = A[c] * W[c]^T + b[c].
// 8 waves (4M x 2N), BK=32, 48 KiB LDS dbuf, both-sides slot swizzle,
// packed LDS-transpose epilogue (full-128B-line dwordx4 stores).
// Block mapping keeps the 16 blocks (8n x 2c) sharing an A-panel XCD-co-resident.
// NOTE: A and C must NOT alias (in-dispatch cross-block RW race otherwise).

template <int K>
__global__ __launch_bounds__(512, 4) void gemm_bc(const unsigned short* __restrict__ Abase,
                                                  size_t aCritStride,
                                                  const unsigned short* __restrict__ Wbase,
                                                  const float* __restrict__ biasBase,
                                                  unsigned short* __restrict__ Cbase) {
  constexpr int NT = K / 32;
  __shared__ unsigned short As[2][256][32];  // 32 KiB
  __shared__ unsigned short Bs[2][128][32];  // 16 KiB  (48 KiB pool, reused by epilogue)

  const int tid  = threadIdx.x;
  const int lane = tid & 63;
  const int wave = tid >> 6;
  const int wm = wave >> 1;   // 0..3 -> rows [wm*64, wm*64+64)
  const int wn = wave & 1;    // 0..1 -> cols [wn*64, wn*64+64)

  const int bid = (int)blockIdx.x;
  const int L = (bid & 7) * 128 + (bid >> 3);
  const int n = L & 7;
  const int cidx = (L >> 3) & 1;
  const int m = L >> 4;
  const int mBase = m * 256;
  const int nBase = n * 128;

  const unsigned short* A = Abase + aCritStride * (size_t)cidx;
  const unsigned short* W = Wbase + (size_t)cidx * HDIM * K;
  const float* bias = biasBase + cidx * HDIM;
  unsigned short* C = Cbase + (size_t)cidx * BATCH * HDIM;

  auto stage = [&](int buf, int kt) {
    #pragma unroll
    for (int i = 0; i < 2; ++i) {
      const int flat = i * 512 + tid;
      const int row  = flat >> 2;
      const int ls   = (flat & 3) ^ ((row >> 1) & 3);
      gload_lds16(A + (size_t)(mBase + row) * K + kt * 32 + ls * 8,
                  &As[buf][0][0] + (size_t)flat * 8);
    }
    {
      const int row = tid >> 2;
      const int ls  = (tid & 3) ^ ((row >> 1) & 3);
      gload_lds16(W + (size_t)(nBase + row) * K + kt * 32 + ls * 8,
                  &Bs[buf][0][0] + (size_t)tid * 8);
    }
  };

  f32x4 acc[4][4];
  #pragma unroll
  for (int fm = 0; fm < 4; ++fm)
    #pragma unroll
    for (int fn = 0; fn < 4; ++fn) {
      f32x4 z = {0.f, 0.f, 0.f, 0.f};
      acc[fm][fn] = z;
    }

  stage(0, 0);
  __syncthreads();

  for (int t = 0; t < NT; ++t) {
    const int buf = t & 1;
    if (t + 1 < NT) stage(buf ^ 1, t + 1);

    short8 af[4], bf[4];
    #pragma unroll
    for (int fm = 0; fm < 4; ++fm) {
      const int r  = wm * 64 + fm * 16 + (lane & 15);
      const int ps = (lane >> 4) ^ ((r >> 1) & 3);
      af[fm] = *(const short8*)&As[buf][r][ps * 8];
    }
    #pragma unroll
    for (int fn = 0; fn < 4; ++fn) {
      const int r  = wn * 64 + fn * 16 + (lane & 15);
      const int ps = (lane >> 4) ^ ((r >> 1) & 3);
      bf[fn] = *(const short8*)&Bs[buf][r][ps * 8];
    }

    __builtin_amdgcn_s_setprio(1);
    #pragma unroll
    for (int fm = 0; fm < 4; ++fm)
      #pragma unroll
      for (int fn = 0; fn < 4; ++fn)
        acc[fm][fn] = __builtin_amdgcn_mfma_f32_16x16x32_bf16(af[fm], bf[fn],
                                                              acc[fm][fn], 0, 0, 0);
    __builtin_amdgcn_s_setprio(0);
    __syncthreads();
  }

  // ---- packed epilogue: LDS transpose -> full-128B-line dwordx4 stores ----
  __syncthreads();  // all waves done reading As/Bs before patch overwrite
  unsigned short* patch = ((unsigned short*)&As[0][0][0]) + wave * 2304;  // 32x72 shorts

  float bcol[4];
  #pragma unroll
  for (int fn = 0; fn < 4; ++fn)
    bcol[fn] = bias[nBase + wn * 64 + fn * 16 + (lane & 15)];

  const int cBase = nBase + wn * 64;

  #pragma unroll
  for (int p = 0; p < 2; ++p) {
    #pragma unroll
    for (int f2 = 0; f2 < 2; ++f2) {
      const int fm = p * 2 + f2;
      #pragma unroll
      for (int fn = 0; fn < 4; ++fn) {
        const int rl = f2 * 16 + (lane >> 4) * 4;
        const int cl = fn * 16 + (lane & 15);
        #pragma unroll
        for (int j = 0; j < 4; ++j)
          patch[(rl + j) * 72 + cl] = f2bf(acc[fm][fn][j] + bcol[fn]);
      }
    }
    #pragma unroll
    for (int k = 0; k < 4; ++k) {
      const int rl = k * 8 + (lane >> 3);
      const short8 v = *(const short8*)&patch[rl * 72 + (lane & 7) * 8];
      const int rowg = mBase + wm * 64 + p * 32 + rl;
      *(short8*)(C + (size_t)rowg * HDIM + cBase + (lane & 7) * 8) = v;
    }
  }
}

// ---------------- critic-batched LayerNorm + ReLU (+ head) -----------------

template <bool HEAD>
__global__ __launch_bounds__(256) void ln_bc(const unsigned short* __restrict__ Xb,
                                             const float* __restrict__ gB,
                                             const float* __restrict__ btB,
                                             unsigned short* __restrict__ Yb,
                                             const float* __restrict__ WhB,
                                             const float* __restrict__ qtB,
                                             float* __restrict__ outB) {
  const int gb = blockIdx.x;
  const int c = gb >> 14;                 // BATCH = 2^14
  const int row = gb & (BATCH - 1);
  const unsigned short* X = Xb + ((size_t)c * BATCH + row) * HDIM;
  const float* g   = gB + c * HDIM;
  const float* bta = btB + c * HDIM;

  const int tid = threadIdx.x;
  const int lane = tid & 63;
  const int wave = tid >> 6;
  __shared__ float rs_[4], rq_[4], rp_[4];

  const ushort4 xv = ((const ushort4*)X)[tid];
  const float x0 = bf2f(xv.x), x1 = bf2f(xv.y), x2 = bf2f(xv.z), x3 = bf2f(xv.w);
  float s = x0 + x1 + x2 + x3;
  float q = x0 * x0 + x1 * x1 + x2 * x2 + x3 * x3;
  #pragma unroll
  for (int off = 32; off; off >>= 1) {
    s += __shfl_xor(s, off);
    q += __shfl_xor(q, off);
  }
  if (lane == 0) { rs_[wave] = s; rq_[wave] = q; }
  __syncthreads();
  s = rs_[0] + rs_[1] + rs_[2] + rs_[3];
  q = rq_[0] + rq_[1] + rq_[2] + rq_[3];
  const float mu = s * (1.0f / 1024.0f);
  const float var = q * (1.0f / 1024.0f) - mu * mu;
  const float rsig = rsqrtf(var + 1e-5f);

  const float4 gv = ((const float4*)g)[tid];
  const float4 bv = ((const float4*)bta)[tid];
  const float y0 = fmaxf((x0 - mu) * rsig * gv.x + bv.x, 0.0f);
  const float y1 = fmaxf((x1 - mu) * rsig * gv.y + bv.y, 0.0f);
  const float y2 = fmaxf((x2 - mu) * rsig * gv.z + bv.z, 0.0f);
  const float y3 = fmaxf((x3 - mu) * rsig * gv.w + bv.w, 0.0f);

  if constexpr (!HEAD) {
    ushort4 o;
    o.x = f2bf(y0); o.y = f2bf(y1); o.z = f2bf(y2); o.w = f2bf(y3);
    ((ushort4*)(Yb + ((size_t)c * BATCH + row) * HDIM))[tid] = o;
  } else {
    const float* Wh = WhB + c * (HDIM + QED);
    const float4 wv = ((const float4*)Wh)[tid];
    float p = y0 * wv.x + y1 * wv.y + y2 * wv.z + y3 * wv.w;
    #pragma unroll
    for (int off = 32; off; off >>= 1) p += __shfl_xor(p, off);
    if (lane == 0) rp_[wave] = p;
    __syncthreads();
    if (tid < 64) {
      const float qf = rp_[0] + rp_[1] + rp_[2] + rp_[3];
      outB[((size_t)c * BATCH + row) * NQD + tid] = qf + qtB[c * 64 + tid];
    }
  }
}

// ---------------- launch ----------------

extern "C" void kernel_launch(void* const* d_in, const int* in_sizes, int n_in,
                              void* d_out, int out_size, void* d_ws, size_t ws_size,
                              hipStream_t stream) {
  (void)in_sizes; (void)n_in; (void)out_size; (void)ws_size;
  const float* state  = (const float*)d_in[0];
  const float* action = (const float*)d_in[1];
  const float* We1 = (const float*)d_in[2];
  const float* be1 = (const float*)d_in[3];
  const float* We2 = (const float*)d_in[4];
  const float* be2 = (const float*)d_in[5];
  const float* Wf1 = (const float*)d_in[6];
  const float* bW1 = (const float*)d_in[7];
  const float* g1  = (const float*)d_in[8];
  const float* bt1 = (const float*)d_in[9];
  const float* Wf2 = (const float*)d_in[10];
  const float* bW2 = (const float*)d_in[11];
  const float* g2  = (const float*)d_in[12];
  const float* bt2 = (const float*)d_in[13];
  const float* Wh  = (const float*)d_in[14];
  const float* bh  = (const float*)d_in[15];
  float* out = (float*)d_out;

  char* ws = (char*)d_ws;
  unsigned short* xb   = (unsigned short*)(ws);               // BATCH*576 bf16   (18,874,368 B)
  unsigned short* w1b  = (unsigned short*)(ws + 18874368);    // 2*1024*576 bf16  (2,359,296 B)
  unsigned short* w2b  = (unsigned short*)(ws + 21233664);    // 2*1024*1024 bf16 (4,194,304 B)
  float*          qtw  = (float*)(ws + 25427968);             // 2*64 f32 (512 B)
  unsigned short* ha   = (unsigned short*)(ws + 25428480);    // 2*BATCH*1024 bf16 -> ends 92,537,344
  unsigned short* hb   = (unsigned short*)(ws + 92537344);    // 2*BATCH*1024 bf16 -> ends 159,646,208

  prep_all<<<2080, 256, 0, stream>>>(state, action, xb, Wf1, w1b, Wf2, w2b,
                                     We1, be1, We2, be2, Wh, bh, qtw);

  // layer 1, both critics (A shared across critics): ha = x @ W1^T + b1
  gemm_bc<XDIM><<<1024, 512, 0, stream>>>(xb, 0, w1b, bW1, ha);
  ln_bc<false><<<2 * BATCH, 256, 0, stream>>>(ha, g1, bt1, hb, nullptr, nullptr, nullptr);
  // layer 2, both critics: ha = hb @ W2^T + b2 ; then LN+head -> out
  gemm_bc<HDIM><<<1024, 512, 0, stream>>>(hb, (size_t)BATCH * HDIM, w2b, bW2, ha);
  ln_bc<true><<<2 * BATCH, 256, 0, stream>>>(ha, g2, bt2, nullptr, Wh, qtw, out);
}